// Round 9
// baseline (65.117 us; speedup 1.0000x reference)
//
#include <hip/hip_runtime.h>
#include <hip/hip_bf16.h>
#include <math.h>

#define KSIZE 11
#define PAD 5

struct GaussW { float w[KSIZE]; };

#define B_    4
#define D_    160
#define H_    192
#define W_    192
#define W4_   48
#define PSTR4 (H_ * W4_)       // plane stride in float4 / ushort4 units

static __device__ inline unsigned short f2bf(float f) {
    __hip_bfloat16 h = __float2bfloat16(f);
    return __builtin_bit_cast(unsigned short, h);
}
static __device__ inline float4 bf4_to_f4(ushort4 u) {
    return make_float4(__uint_as_float((unsigned)u.x << 16),
                       __uint_as_float((unsigned)u.y << 16),
                       __uint_as_float((unsigned)u.z << 16),
                       __uint_as_float((unsigned)u.w << 16));
}
static __device__ inline ushort4 f4_to_bf4(float4 a) {
    return make_ushort4(f2bf(a.x), f2bf(a.y), f2bf(a.z), f2bf(a.w));
}

// ---------------- Kernel A: W+H fused, H-sliding window, no LDS -----------
// Each thread owns a CH-high column of one w4. Per h-step: 5-float4 register
// W-conv window (masked/clamped, plane-invariant precompute), push result
// into an 11-deep %11-static ring, emit H-conv as bf16. No LDS, no barriers;
// latency hidden by per-thread ILP.
template <int CH>
__global__ __launch_bounds__(256) void blur_wh_slide(const float4* __restrict__ src,
                                                     ushort4* __restrict__ wsb,
                                                     GaussW g, int ncol) {
    const int tid = blockIdx.x * blockDim.x + threadIdx.x;
    const int col = tid % ncol;        // ncol = B*D*W4 (multiple of 256)
    const int ch  = tid / ncol;        // block-uniform (ncol % 256 == 0)
    const int h0  = ch * CH;
    const int w4  = col % W4_;
    const int pd  = col / W4_;         // b*D + d

    const float4* pbase = src + pd * PSTR4;
    ushort4* obase = wsb + pd * PSTR4 + w4;

    // Plane-invariant W-window geometry: clamped offsets + 0/1 masks.
    int   off[5];
    float fm[5];
#pragma unroll
    for (int u = 0; u < 5; ++u) {
        int q = w4 - 2 + u;
        off[u] = min(max(q, 0), W4_ - 1);
        fm[u]  = (q >= 0 && q < W4_) ? 1.f : 0.f;
    }

    // W-conv of row h -> one float4 (output cols w4*4..w4*4+3).
    auto wload = [&](int h) -> float4 {
        float4 r = make_float4(0.f, 0.f, 0.f, 0.f);
        if (h >= 0 && h < H_) {        // block-uniform branch
            const float4* row = pbase + h * W4_;
            float win[20];
#pragma unroll
            for (int u = 0; u < 5; ++u) {
                float4 v = row[off[u]];
                float m = fm[u];
                win[4*u+0] = v.x * m; win[4*u+1] = v.y * m;
                win[4*u+2] = v.z * m; win[4*u+3] = v.w * m;
            }
#pragma unroll
            for (int t = 0; t < KSIZE; ++t) {
                float wt = g.w[t];
                r.x += wt * win[3 + t]; r.y += wt * win[4 + t];
                r.z += wt * win[5 + t]; r.w += wt * win[6 + t];
            }
        }
        return r;
    };

    float4 ring[KSIZE];
    // Preload rows h0-5 .. h0+4 into ring[0..9].
#pragma unroll
    for (int j = 0; j < KSIZE - 1; ++j) ring[j] = wload(h0 - PAD + j);

#pragma unroll
    for (int k = 0; k < CH; ++k) {
        ring[(KSIZE - 1 + k) % KSIZE] = wload(h0 + k + PAD);

        float4 a = make_float4(0.f, 0.f, 0.f, 0.f);
#pragma unroll
        for (int t = 0; t < KSIZE; ++t) {
            float4 u = ring[(k + t) % KSIZE];   // static after full unroll
            float wt = g.w[t];
            a.x += wt * u.x; a.y += wt * u.y;
            a.z += wt * u.z; a.w += wt * u.w;
        }
        obase[(h0 + k) * W4_] = f4_to_bf4(a);
    }
}

// ---------------- Kernel B: D-axis sliding window (bf16 -> f32) ------------
template <int STR4, int LEN, int CH>
__global__ __launch_bounds__(256) void blur_d_slide(const ushort4* __restrict__ src,
                                                    float4* __restrict__ dst,
                                                    GaussW g, int ncol) {
    int tid = blockIdx.x * blockDim.x + threadIdx.x;
    int col = tid % ncol;
    int chunk = tid / ncol;
    int c0 = chunk * CH;
    int inner = col % STR4;
    int outer = col / STR4;
    int base = outer * (LEN * STR4) + inner;

    float4 ring[KSIZE];
#pragma unroll
    for (int j = 0; j < KSIZE - 1; ++j) {
        int cc = c0 - PAD + j;
        float4 v = make_float4(0.f, 0.f, 0.f, 0.f);
        if (cc >= 0 && cc < LEN) v = bf4_to_f4(src[base + cc * STR4]);
        ring[j] = v;
    }
#pragma unroll
    for (int k = 0; k < CH; ++k) {
        int cc = c0 + k + PAD;
        float4 v = make_float4(0.f, 0.f, 0.f, 0.f);
        if (cc < LEN) v = bf4_to_f4(src[base + cc * STR4]);
        ring[(KSIZE - 1 + k) % KSIZE] = v;

        float4 acc = make_float4(0.f, 0.f, 0.f, 0.f);
#pragma unroll
        for (int t = 0; t < KSIZE; ++t) {
            float4 u = ring[(k + t) % KSIZE];   // static after full unroll
            float wt = g.w[t];
            acc.x += wt * u.x; acc.y += wt * u.y;
            acc.z += wt * u.z; acc.w += wt * u.w;
        }
        dst[base + (c0 + k) * STR4] = acc;
    }
}

// ---------------- Dense fallback (ws too small; never expected) ------------
__global__ void blur_dense_fallback(const float* __restrict__ src,
                                    float* __restrict__ dst,
                                    GaussW g, int B, int D, int H, int W) {
    long n = (long)B * D * H * W;
    long i = (long)blockIdx.x * blockDim.x + threadIdx.x;
    if (i >= n) return;
    int w = (int)(i % W);
    long r = i / W;
    int h = (int)(r % H); r /= H;
    int d = (int)(r % D);
    int b = (int)(r / D);

    float acc = 0.f;
    for (int td = 0; td < KSIZE; ++td) {
        int dd = d + td - PAD;
        if (dd < 0 || dd >= D) continue;
        for (int th = 0; th < KSIZE; ++th) {
            int hh = h + th - PAD;
            if (hh < 0 || hh >= H) continue;
            float wdh = g.w[td] * g.w[th];
            const float* row = src + (((long)b * D + dd) * H + hh) * W;
            for (int tw = 0; tw < KSIZE; ++tw) {
                int ww = w + tw - PAD;
                if (ww < 0 || ww >= W) continue;
                acc += wdh * g.w[tw] * row[ww];
            }
        }
    }
    dst[i] = acc;
}

extern "C" void kernel_launch(void* const* d_in, const int* in_sizes, int n_in,
                              void* d_out, int out_size, void* d_ws, size_t ws_size,
                              hipStream_t stream) {
    const float* x = (const float*)d_in[0];
    float* out = (float*)d_out;
    (void)in_sizes; (void)n_in; (void)out_size;

    const long n = (long)B_ * D_ * H_ * W_;   // 23,592,960

    GaussW g;
    {
        double tmp[KSIZE], s = 0.0;
        for (int i = 0; i < KSIZE; ++i) {
            double dd = (double)(i - PAD);
            tmp[i] = exp(-(dd * dd) / (2.0 * 1.5 * 1.5));
            s += tmp[i];
        }
        for (int i = 0; i < KSIZE; ++i) g.w[i] = (float)(tmp[i] / s);
    }

    if (ws_size >= (size_t)n * sizeof(unsigned short)) {
        // A: x (f32) -> ws (bf16), W+H fused, H-sliding window, no LDS.
        {
            const int ncol = B_ * D_ * W4_;        // 30720 (multiple of 256)
            const int threads = ncol * (H_ / 32);  // 184320
            blur_wh_slide<32><<<threads / 256, 256, 0, stream>>>(
                (const float4*)x, (ushort4*)d_ws, g, ncol);
        }
        // B: ws (bf16) -> out (f32), sliding window along D.
        {
            const int ncol = B_ * H_ * W4_;        // 36864 (multiple of 256)
            const int threads = ncol * (D_ / 32);  // 184320
            blur_d_slide<9216, 160, 32><<<threads / 256, 256, 0, stream>>>(
                (const ushort4*)d_ws, (float4*)out, g, ncol);
        }
    } else {
        long gridN = (n + 255) / 256;
        blur_dense_fallback<<<(int)gridN, 256, 0, stream>>>(x, out, g, B_, D_, H_, W_);
    }
}

// Round 11
// 57.251 us; speedup vs baseline: 1.1374x; 1.1374x over previous
//
#include <hip/hip_runtime.h>
#include <hip/hip_bf16.h>
#include <math.h>

#define KSIZE 11
#define PAD 5

struct GaussW { float w[KSIZE]; };

#define B_    4
#define D_    160
#define H_    192
#define W_    192
#define W4_   48

typedef float floatx4 __attribute__((ext_vector_type(4)));

// ---------------- Kernel A: per-plane fused W+H blur (f32 -> bf16) ---------
// R6-proven config (best measured): LDS-staged input plane, register
// prefetch of next plane, bf16 wtb (b64 conflict-free), 2 barriers/plane,
// TH=48, DCH=5 -> 1536 blocks, 27.4 KB LDS -> 5 blocks/CU.
#define TW4    16              // tile width in float4 (64 floats)
#define TH     48              // tile height (rows)
#define DCH    5               // planes per block
#define NH     (H_ / TH)       // 4
#define NWT    (W_ / (TW4*4))  // 3
#define NDC    (D_ / DCH)      // 32
#define NBLK_A (B_ * NH * NWT * NDC)   // 1536
#define INROWS (TH + 10)       // 58
#define INW4   (TW4 + 4)       // 20
#define IN_STR4 21             // lds_in row stride in float4
#define WT_STR4 17             // wtb row stride in ushort4
#define NSTAGE (INROWS * INW4) // 1160
#define PSTR4  (H_ * W4_)      // plane stride in float4 / ushort4 units

static __device__ inline unsigned short f2bf(float f) {
    __hip_bfloat16 h = __float2bfloat16(f);
    return __builtin_bit_cast(unsigned short, h);
}
static __device__ inline float4 bf4_to_f4(ushort4 u) {
    return make_float4(__uint_as_float((unsigned)u.x << 16),
                       __uint_as_float((unsigned)u.y << 16),
                       __uint_as_float((unsigned)u.z << 16),
                       __uint_as_float((unsigned)u.w << 16));
}

__global__ __launch_bounds__(256) void blur_wh3(const float4* __restrict__ src,
                                                ushort4* __restrict__ wsb,
                                                GaussW g) {
    __shared__ __align__(16) float  lds_in[INROWS * IN_STR4 * 4];  // 19488 B
    __shared__ __align__(16) ushort4 wtb[INROWS * WT_STR4];        //  7888 B

    // XCD swizzle (1536 % 8 == 0): halo-sharing neighbor tiles adjacent.
    int bid = blockIdx.x;
    int L = (bid & 7) * (NBLK_A / 8) + (bid >> 3);
    int wx = L % NWT; L /= NWT;
    int hy = L % NH;  L /= NH;
    int dc = L % NDC;
    int b  = L / NDC;

    const int h0  = hy * TH;
    const int w0q = wx * TW4;
    const int d0  = dc * DCH;
    const int tid = threadIdx.x;

    const int wr   = tid >> 2;            // W-conv row 0..63 (valid < 58)
    const int wq   = (tid & 3) * 4;       // f4 col group base {0,4,8,12}
    const bool wact = (wr < INROWS);

    const int c4  = tid & 15;             // H-conv col
    const int grp = tid >> 4;             // rows 3grp..3grp+2

    const float4* pin = src + (b * D_ + d0) * PSTR4;
    ushort4* pout = wsb + (b * D_ + d0) * PSTR4 + (h0 + 3 * grp) * W4_ + w0q + c4;

    float4 pf[5];
    auto issue = [&](const float4* plane) {
#pragma unroll
        for (int j = 0; j < 5; ++j) {
            pf[j] = make_float4(0.f, 0.f, 0.f, 0.f);
            int it = tid + j * 256;
            if (it < NSTAGE) {
                int ir = it / INW4, jc = it - ir * INW4;
                int h = h0 - PAD + ir;
                int q = w0q - 2 + jc;
                if (h >= 0 && h < H_ && q >= 0 && q < W4_)
                    pf[j] = plane[h * W4_ + q];
            }
        }
    };
    auto stage_write = [&]() {
#pragma unroll
        for (int j = 0; j < 5; ++j) {
            int it = tid + j * 256;
            if (it < NSTAGE) {
                int ir = it / INW4, jc = it - ir * INW4;
                *(float4*)&lds_in[(ir * IN_STR4 + jc) * 4] = pf[j];
            }
        }
    };

    issue(pin);                 // plane d0
    stage_write();
    issue(pin + PSTR4);         // plane d0+1
    __syncthreads();

    for (int p = 0; p < DCH; ++p) {
        // ---- W-conv plane p: lds_in -> wtb (bf16) ----
        if (wact) {
            float win[32];
            const float* row = &lds_in[(wr * IN_STR4 + wq) * 4];
#pragma unroll
            for (int u = 0; u < 8; ++u) {
                float4 v = *(const float4*)&row[u * 4];
                win[4*u+0] = v.x; win[4*u+1] = v.y;
                win[4*u+2] = v.z; win[4*u+3] = v.w;
            }
            float o[16];
#pragma unroll
            for (int i = 0; i < 16; ++i) {
                float a = 0.f;
#pragma unroll
                for (int t = 0; t < KSIZE; ++t) a += g.w[t] * win[i + 3 + t];
                o[i] = a;
            }
            ushort4* wrow = &wtb[wr * WT_STR4 + wq];
#pragma unroll
            for (int c = 0; c < 4; ++c)
                wrow[c] = make_ushort4(f2bf(o[4*c]), f2bf(o[4*c+1]),
                                       f2bf(o[4*c+2]), f2bf(o[4*c+3]));
        }
        __syncthreads();   // wtb ready; lds_in fully consumed

        // ---- stage plane p+1 (overlaps H-conv), issue plane p+2 ----
        if (p + 1 < DCH) stage_write();
        if (p + 2 < DCH) issue(pin + (p + 2) * PSTR4);

        // ---- H-conv plane p: wtb -> global bf16 (3 rows/thread) ----
        {
            float4 a0 = make_float4(0.f,0.f,0.f,0.f);
            float4 a1 = a0, a2 = a0;
#pragma unroll
            for (int j = 0; j < 13; ++j) {
                float4 v = bf4_to_f4(wtb[(3*grp + j) * WT_STR4 + c4]);
                if (j <= 10) {
                    float wt_ = g.w[j];
                    a0.x += wt_*v.x; a0.y += wt_*v.y; a0.z += wt_*v.z; a0.w += wt_*v.w;
                }
                if (j >= 1 && j <= 11) {
                    float wt_ = g.w[j-1];
                    a1.x += wt_*v.x; a1.y += wt_*v.y; a1.z += wt_*v.z; a1.w += wt_*v.w;
                }
                if (j >= 2) {
                    float wt_ = g.w[j-2];
                    a2.x += wt_*v.x; a2.y += wt_*v.y; a2.z += wt_*v.z; a2.w += wt_*v.w;
                }
            }
            ushort4* op = pout + p * PSTR4;
            op[0      ] = make_ushort4(f2bf(a0.x), f2bf(a0.y), f2bf(a0.z), f2bf(a0.w));
            op[W4_    ] = make_ushort4(f2bf(a1.x), f2bf(a1.y), f2bf(a1.z), f2bf(a1.w));
            op[2 * W4_] = make_ushort4(f2bf(a2.x), f2bf(a2.y), f2bf(a2.z), f2bf(a2.w));
        }
        __syncthreads();   // lds_in free for next stage; wtb consumed
    }
}

// ---------------- Kernel B: D-axis sliding window (bf16 -> f32) ------------
// R9/R10: CH=16 (1440 blocks = 5.6/CU for latency hiding) + nontemporal
// output stores (out never re-read -> keep x+ws L3-resident).
template <int STR4, int LEN, int CH>
__global__ __launch_bounds__(256) void blur_d_slide(const ushort4* __restrict__ src,
                                                    float4* __restrict__ dst,
                                                    GaussW g, int ncol) {
    int tid = blockIdx.x * blockDim.x + threadIdx.x;
    int col = tid % ncol;
    int chunk = tid / ncol;
    int c0 = chunk * CH;
    int inner = col % STR4;
    int outer = col / STR4;
    int base = outer * (LEN * STR4) + inner;

    float4 ring[KSIZE];
#pragma unroll
    for (int j = 0; j < KSIZE - 1; ++j) {
        int cc = c0 - PAD + j;
        float4 v = make_float4(0.f, 0.f, 0.f, 0.f);
        if (cc >= 0 && cc < LEN) v = bf4_to_f4(src[base + cc * STR4]);
        ring[j] = v;
    }
#pragma unroll
    for (int k = 0; k < CH; ++k) {
        int cc = c0 + k + PAD;
        float4 v = make_float4(0.f, 0.f, 0.f, 0.f);
        if (cc < LEN) v = bf4_to_f4(src[base + cc * STR4]);
        ring[(KSIZE - 1 + k) % KSIZE] = v;

        float4 acc = make_float4(0.f, 0.f, 0.f, 0.f);
#pragma unroll
        for (int t = 0; t < KSIZE; ++t) {
            float4 u = ring[(k + t) % KSIZE];   // static after full unroll
            float wt = g.w[t];
            acc.x += wt * u.x; acc.y += wt * u.y;
            acc.z += wt * u.z; acc.w += wt * u.w;
        }
        floatx4 av; av.x = acc.x; av.y = acc.y; av.z = acc.z; av.w = acc.w;
        __builtin_nontemporal_store(av, (floatx4*)&dst[base + (c0 + k) * STR4]);
    }
}

// ---------------- Dense fallback (ws too small; never expected) ------------
__global__ void blur_dense_fallback(const float* __restrict__ src,
                                    float* __restrict__ dst,
                                    GaussW g, int B, int D, int H, int W) {
    long n = (long)B * D * H * W;
    long i = (long)blockIdx.x * blockDim.x + threadIdx.x;
    if (i >= n) return;
    int w = (int)(i % W);
    long r = i / W;
    int h = (int)(r % H); r /= H;
    int d = (int)(r % D);
    int b = (int)(r / D);

    float acc = 0.f;
    for (int td = 0; td < KSIZE; ++td) {
        int dd = d + td - PAD;
        if (dd < 0 || dd >= D) continue;
        for (int th = 0; th < KSIZE; ++th) {
            int hh = h + th - PAD;
            if (hh < 0 || hh >= H) continue;
            float wdh = g.w[td] * g.w[th];
            const float* row = src + (((long)b * D + dd) * H + hh) * W;
            for (int tw = 0; tw < KSIZE; ++tw) {
                int ww = w + tw - PAD;
                if (ww < 0 || ww >= W) continue;
                acc += wdh * g.w[tw] * row[ww];
            }
        }
    }
    dst[i] = acc;
}

extern "C" void kernel_launch(void* const* d_in, const int* in_sizes, int n_in,
                              void* d_out, int out_size, void* d_ws, size_t ws_size,
                              hipStream_t stream) {
    const float* x = (const float*)d_in[0];
    float* out = (float*)d_out;
    (void)in_sizes; (void)n_in; (void)out_size;

    const long n = (long)B_ * D_ * H_ * W_;   // 23,592,960

    GaussW g;
    {
        double tmp[KSIZE], s = 0.0;
        for (int i = 0; i < KSIZE; ++i) {
            double dd = (double)(i - PAD);
            tmp[i] = exp(-(dd * dd) / (2.0 * 1.5 * 1.5));
            s += tmp[i];
        }
        for (int i = 0; i < KSIZE; ++i) g.w[i] = (float)(tmp[i] / s);
    }

    if (ws_size >= (size_t)n * sizeof(unsigned short)) {
        // A: x (f32) -> ws (bf16), fused W+H per plane, LDS-staged input.
        blur_wh3<<<NBLK_A, 256, 0, stream>>>((const float4*)x, (ushort4*)d_ws, g);
        // B: ws (bf16) -> out (f32), sliding window along D, CH=16.
        const int ncol = B_ * H_ * W4_;           // 36864 (multiple of 256)
        const int threads = ncol * (D_ / 16);     // 368640
        blur_d_slide<9216, 160, 16><<<threads / 256, 256, 0, stream>>>(
            (const ushort4*)d_ws, (float4*)out, g, ncol);
    } else {
        long gridN = (n + 255) / 256;
        blur_dense_fallback<<<(int)gridN, 256, 0, stream>>>(x, out, g, B_, D_, H_, W_);
    }
}